// Round 1
// baseline (746.948 us; speedup 1.0000x reference)
//
#include <hip/hip_runtime.h>
#include <hip/hip_bf16.h>

// GraphSAGE: 2x SAGEConv(mean) + ReLU, then linear classifier.
// Strategy: build CSR (by dst) per call, CSR mean-aggregate, fused
// (self+neigh) register-tiled fp32 GEMMs.

#define N_FEATS 128
#define N_CLASSES 64

// ---------------- CSR build ----------------

__global__ void k_count(const int* __restrict__ dst, int* __restrict__ cnt, int E) {
    int i = blockIdx.x * blockDim.x + threadIdx.x;
    if (i < E) atomicAdd(&cnt[dst[i]], 1);
}

__global__ void k_scan_local(const int* __restrict__ cnt, int* __restrict__ excl,
                             int* __restrict__ blksum, int N) {
    __shared__ int s[256];
    int t = threadIdx.x;
    int i = blockIdx.x * 256 + t;
    int v = (i < N) ? cnt[i] : 0;
    s[t] = v;
    __syncthreads();
    for (int off = 1; off < 256; off <<= 1) {
        int x = 0;
        if (t >= off) x = s[t - off];
        __syncthreads();
        if (t >= off) s[t] += x;
        __syncthreads();
    }
    if (i < N) excl[i] = s[t] - v;       // exclusive
    if (t == 255) blksum[blockIdx.x] = s[255];
}

__global__ void k_scan_blk(int* __restrict__ blk, int NB) {
    __shared__ int s[512];
    int t = threadIdx.x;
    int v = (t < NB) ? blk[t] : 0;
    s[t] = v;
    __syncthreads();
    for (int off = 1; off < 512; off <<= 1) {
        int x = 0;
        if (t >= off) x = s[t - off];
        __syncthreads();
        if (t >= off) s[t] += x;
        __syncthreads();
    }
    if (t < NB) blk[t] = s[t] - v;       // exclusive block offsets
}

__global__ void k_scan_add(int* __restrict__ excl, const int* __restrict__ blk,
                           int* __restrict__ cursor, int N, int E) {
    int i = blockIdx.x * 256 + threadIdx.x;
    if (i < N) {
        int v = excl[i] + blk[blockIdx.x];
        excl[i] = v;
        cursor[i] = v;
    }
    if (blockIdx.x == 0 && threadIdx.x == 0) excl[N] = E;
}

__global__ void k_fill(const int* __restrict__ src, const int* __restrict__ dst,
                       int* __restrict__ cursor, int* __restrict__ col, int E) {
    int i = blockIdx.x * blockDim.x + threadIdx.x;
    if (i < E) {
        int p = atomicAdd(&cursor[dst[i]], 1);
        col[p] = src[i];
    }
}

// ---------------- mean aggregation (CSR gather) ----------------
// one block (128 threads) per destination node; thread f owns feature f.
__global__ __launch_bounds__(128) void k_agg(const float* __restrict__ h,
                                             const int* __restrict__ row_start,
                                             const int* __restrict__ col,
                                             float* __restrict__ hn, int N) {
    int n = blockIdx.x;
    int f = threadIdx.x;
    int beg = row_start[n];
    int end = row_start[n + 1];
    __shared__ int s[128];
    float acc = 0.f;
    for (int j0 = beg; j0 < end; j0 += 128) {
        int m = min(128, end - j0);
        if (f < m) s[f] = col[j0 + f];
        __syncthreads();
        for (int j = 0; j < m; ++j)
            acc += h[(size_t)s[j] * N_FEATS + f];
        __syncthreads();
    }
    float inv = 1.0f / fmaxf((float)(end - beg), 1.0f);
    hn[(size_t)n * N_FEATS + f] = acc * inv;
}

// ---------------- fused GEMM:  C = act(A1@W1 [+ A2@W2] + b) ----------------
// block: 64 rows x COLS cols; 256 threads as 16x16; each thread 4 rows x (COLS/16) cols.
template <int COLS, bool FUSE2, bool RELU>
__global__ __launch_bounds__(256) void k_gemm(const float* __restrict__ A1,
                                              const float* __restrict__ W1,
                                              const float* __restrict__ A2,
                                              const float* __restrict__ W2,
                                              const float* __restrict__ bias,
                                              float* __restrict__ C, int M) {
    constexpr int TN = COLS / 16;
    __shared__ float As[32][68];        // [k][row], padded, rows stay 16B aligned
    __shared__ float Bs[32][COLS];      // [k][col]
    const int t = threadIdx.x;
    const int tx = t & 15;
    const int ty = t >> 4;
    const int row0 = blockIdx.x * 64;

    float acc[4][TN];
#pragma unroll
    for (int i = 0; i < 4; ++i)
#pragma unroll
        for (int n = 0; n < TN; ++n) acc[i][n] = 0.f;

    const int nPhases = FUSE2 ? 2 : 1;
    for (int p = 0; p < nPhases; ++p) {
        const float* __restrict__ A = (p == 0) ? A1 : A2;
        const float* __restrict__ W = (p == 0) ? W1 : W2;
        for (int kt = 0; kt < N_FEATS / 32; ++kt) {
            __syncthreads();
            // stage A tile (64 rows x 32 k), transposed into As[k][row]
#pragma unroll
            for (int i = 0; i < 2; ++i) {
                int l = t * 2 + i;              // 0..511 float4 slots
                int r = l >> 3;                 // 0..63
                int kc = (l & 7) * 4;           // 0,4,...,28
                int row = row0 + r;
                if (row >= M) row = M - 1;
                const float4 v = *(const float4*)&A[(size_t)row * N_FEATS + kt * 32 + kc];
                As[kc + 0][r] = v.x;
                As[kc + 1][r] = v.y;
                As[kc + 2][r] = v.z;
                As[kc + 3][r] = v.w;
            }
            // stage B tile (32 k x COLS), row-major copy
            {
                constexpr int F4_PER_ROW = COLS / 4;
                constexpr int PER_T = (32 * F4_PER_ROW) / 256;
#pragma unroll
                for (int i = 0; i < PER_T; ++i) {
                    int l = t * PER_T + i;
                    int kk = l / F4_PER_ROW;
                    int c4 = (l % F4_PER_ROW) * 4;
                    *(float4*)&Bs[kk][c4] =
                        *(const float4*)&W[(size_t)(kt * 32 + kk) * COLS + c4];
                }
            }
            __syncthreads();
#pragma unroll
            for (int k = 0; k < 32; ++k) {
                float4 a = *(const float4*)&As[k][ty * 4];
                float av[4] = {a.x, a.y, a.z, a.w};
                float wv[TN];
#pragma unroll
                for (int n = 0; n < TN; n += 4) {
                    float4 w = *(const float4*)&Bs[k][tx * TN + n];
                    wv[n + 0] = w.x;
                    wv[n + 1] = w.y;
                    wv[n + 2] = w.z;
                    wv[n + 3] = w.w;
                }
#pragma unroll
                for (int i = 0; i < 4; ++i)
#pragma unroll
                    for (int n = 0; n < TN; ++n)
                        acc[i][n] = fmaf(av[i], wv[n], acc[i][n]);
            }
        }
    }
    // epilogue
#pragma unroll
    for (int i = 0; i < 4; ++i) {
        int row = row0 + ty * 4 + i;
        if (row < M) {
#pragma unroll
            for (int n = 0; n < TN; n += 4) {
                int c = tx * TN + n;
                float4 v;
                v.x = acc[i][n + 0] + bias[c + 0];
                v.y = acc[i][n + 1] + bias[c + 1];
                v.z = acc[i][n + 2] + bias[c + 2];
                v.w = acc[i][n + 3] + bias[c + 3];
                if (RELU) {
                    v.x = fmaxf(v.x, 0.f);
                    v.y = fmaxf(v.y, 0.f);
                    v.z = fmaxf(v.z, 0.f);
                    v.w = fmaxf(v.w, 0.f);
                }
                *(float4*)&C[(size_t)row * COLS + c] = v;
            }
        }
    }
}

extern "C" void kernel_launch(void* const* d_in, const int* in_sizes, int n_in,
                              void* d_out, int out_size, void* d_ws, size_t ws_size,
                              hipStream_t stream) {
    const float* x       = (const float*)d_in[0];
    const float* W_self1 = (const float*)d_in[1];
    const float* W_neigh1= (const float*)d_in[2];
    const float* b1      = (const float*)d_in[3];
    const float* W_self2 = (const float*)d_in[4];
    const float* W_neigh2= (const float*)d_in[5];
    const float* b2      = (const float*)d_in[6];
    const float* W_out   = (const float*)d_in[7];
    const float* b_out   = (const float*)d_in[8];
    const int* edge_src  = (const int*)d_in[9];
    const int* edge_dst  = (const int*)d_in[10];

    const int N = in_sizes[0] / N_FEATS;   // 100000
    const int E = in_sizes[9];             // 1600000
    float* out = (float*)d_out;

    // workspace carve-up (256B aligned)
    char* ws = (char*)d_ws;
    size_t o = 0;
    auto carve = [&](size_t bytes) -> char* {
        char* p = ws + o;
        o += (bytes + 255) & ~(size_t)255;
        return p;
    };
    float* hn       = (float*)carve((size_t)N * N_FEATS * 4);
    float* h        = (float*)carve((size_t)N * N_FEATS * 4);
    int* cnt        = (int*)carve((size_t)N * 4);
    int* row_start  = (int*)carve((size_t)(N + 1) * 4);
    int* cursor     = (int*)carve((size_t)N * 4);
    int* blk        = (int*)carve(512 * 4);
    int* col        = (int*)carve((size_t)E * 4);
    (void)ws_size;

    const int NB = (N + 255) / 256;        // 391 <= 512

    // CSR build
    hipMemsetAsync(cnt, 0, (size_t)N * 4, stream);
    k_count<<<(E + 255) / 256, 256, 0, stream>>>(edge_dst, cnt, E);
    k_scan_local<<<NB, 256, 0, stream>>>(cnt, row_start, blk, N);
    k_scan_blk<<<1, 512, 0, stream>>>(blk, NB);
    k_scan_add<<<NB, 256, 0, stream>>>(row_start, blk, cursor, N, E);
    k_fill<<<(E + 255) / 256, 256, 0, stream>>>(edge_src, edge_dst, cursor, col, E);

    const int GB = (N + 63) / 64;          // gemm row blocks

    // layer 1
    k_agg<<<N, 128, 0, stream>>>(x, row_start, col, hn, N);
    k_gemm<128, true, true><<<GB, 256, 0, stream>>>(x, W_self1, hn, W_neigh1, b1, h, N);
    // layer 2 (in-place over h is safe: each block writes only rows it alone reads)
    k_agg<<<N, 128, 0, stream>>>(h, row_start, col, hn, N);
    k_gemm<128, true, true><<<GB, 256, 0, stream>>>(h, W_self2, hn, W_neigh2, b2, h, N);
    // classifier
    k_gemm<64, false, false><<<GB, 256, 0, stream>>>(h, W_out, nullptr, nullptr, b_out, out, N);
}

// Round 2
// 604.525 us; speedup vs baseline: 1.2356x; 1.2356x over previous
//
#include <hip/hip_runtime.h>
#include <hip/hip_bf16.h>

// GraphSAGE: 2x SAGEConv(mean) + ReLU + linear classifier.
// Round 2: bf16 MFMA GEMMs (16x16x32_bf16), bf16 aggregation gather,
// atomic-free CSR fill via rank trick.

#define N_FEATS 128

typedef __attribute__((ext_vector_type(8))) short bf16x8;
typedef __attribute__((ext_vector_type(4))) float f32x4;

__device__ __forceinline__ ushort f2b(float f) {
    union { float f; unsigned u; } c; c.f = f;
    unsigned u = c.u + 0x7fffu + ((c.u >> 16) & 1u);
    return (ushort)(u >> 16);
}
__device__ __forceinline__ float b2f(ushort b) {
    union { unsigned u; float f; } c; c.u = ((unsigned)b) << 16;
    return c.f;
}

// ---------------- CSR build ----------------

__global__ void k_count(const int* __restrict__ dst, int* __restrict__ cnt,
                        int* __restrict__ rank, int E) {
    int i = blockIdx.x * blockDim.x + threadIdx.x;
    if (i < E) rank[i] = atomicAdd(&cnt[dst[i]], 1);
}

__global__ void k_scan_local(const int* __restrict__ cnt, int* __restrict__ excl,
                             int* __restrict__ blksum, int N) {
    __shared__ int s[256];
    int t = threadIdx.x;
    int i = blockIdx.x * 256 + t;
    int v = (i < N) ? cnt[i] : 0;
    s[t] = v;
    __syncthreads();
    for (int off = 1; off < 256; off <<= 1) {
        int x = 0;
        if (t >= off) x = s[t - off];
        __syncthreads();
        if (t >= off) s[t] += x;
        __syncthreads();
    }
    if (i < N) excl[i] = s[t] - v;
    if (t == 255) blksum[blockIdx.x] = s[255];
}

__global__ void k_scan_blk(int* __restrict__ blk, int NB) {
    __shared__ int s[512];
    int t = threadIdx.x;
    int v = (t < NB) ? blk[t] : 0;
    s[t] = v;
    __syncthreads();
    for (int off = 1; off < 512; off <<= 1) {
        int x = 0;
        if (t >= off) x = s[t - off];
        __syncthreads();
        if (t >= off) s[t] += x;
        __syncthreads();
    }
    if (t < NB) blk[t] = s[t] - v;
}

__global__ void k_scan_add(int* __restrict__ excl, const int* __restrict__ blk,
                           int N, int E) {
    int i = blockIdx.x * 256 + threadIdx.x;
    if (i < N) excl[i] += blk[blockIdx.x];
    if (blockIdx.x == 0 && threadIdx.x == 0) excl[N] = E;
}

__global__ void k_fill(const int* __restrict__ src, const int* __restrict__ dst,
                       const int* __restrict__ row_start, const int* __restrict__ rank,
                       int* __restrict__ col, int E) {
    int i = blockIdx.x * blockDim.x + threadIdx.x;
    if (i < E) {
        int p = row_start[dst[i]] + rank[i];
        col[p] = src[i];
    }
}

// ---------------- dtype conversion ----------------

__global__ void k_f2b4(const float* __restrict__ in, ushort* __restrict__ out, int n4) {
    int i = blockIdx.x * blockDim.x + threadIdx.x;
    if (i < n4) {
        float4 v = ((const float4*)in)[i];
        ushort4 o;
        o.x = f2b(v.x); o.y = f2b(v.y); o.z = f2b(v.z); o.w = f2b(v.w);
        ((ushort4*)out)[i] = o;
    }
}

// W [K][N] fp32 -> Wt [N][K] bf16
__global__ void k_wt(const float* __restrict__ W, ushort* __restrict__ Wt, int K, int N) {
    int i = blockIdx.x * blockDim.x + threadIdx.x;
    if (i < K * N) {
        int k = i / N, n = i % N;
        Wt[n * K + k] = f2b(W[i]);
    }
}

// ---------------- mean aggregation (CSR gather, bf16) ----------------
// 256 threads = 4 waves; wave g handles node blockIdx*4+g; lane owns 2 feats.
__global__ __launch_bounds__(256) void k_agg(const ushort* __restrict__ h,
                                             const int* __restrict__ row_start,
                                             const int* __restrict__ col,
                                             ushort* __restrict__ hn, int N) {
    int g = threadIdx.x >> 6;
    int lane = threadIdx.x & 63;
    int n = blockIdx.x * 4 + g;
    if (n >= N) return;
    int beg = row_start[n], end = row_start[n + 1];
    float ax = 0.f, ay = 0.f;
    for (int j = beg; j < end; ++j) {
        int s = col[j];
        unsigned v = *(const unsigned*)&h[(size_t)s * N_FEATS + lane * 2];
        ax += b2f((ushort)v);
        ay += b2f((ushort)(v >> 16));
    }
    float inv = 1.f / fmaxf((float)(end - beg), 1.f);
    ax *= inv; ay *= inv;
    unsigned o = (unsigned)f2b(ax) | ((unsigned)f2b(ay) << 16);
    *(unsigned*)&hn[(size_t)n * N_FEATS + lane * 2] = o;
}

// ---------------- MFMA GEMM: C = act(A1@W1t' [+ A2@W2t'] + b) ----------------
// A: [M][128] bf16 row-major. Wt: [COLS][128] bf16 (pre-transposed).
// Block tile 128 x COLS, K=128 per phase. 256 threads = 4 waves.
template <int COLS, bool FUSE2, bool RELU, bool OUTB>
__global__ __launch_bounds__(256) void k_mm(const ushort* __restrict__ A1,
                                            const ushort* __restrict__ W1t,
                                            const ushort* __restrict__ A2,
                                            const ushort* __restrict__ W2t,
                                            const float* __restrict__ bias,
                                            void* __restrict__ Cout, int M) {
    constexpr int K = 128;
    constexpr int WGC = (COLS == 128) ? 2 : 1;   // wave grid cols
    constexpr int WTM = (COLS == 128) ? 64 : 32; // wave tile rows
    constexpr int MI = WTM / 16;
    constexpr int NI = 4;                        // 64 cols / 16
    constexpr int LDA = 40;                      // padded stride (halfwords)
    __shared__ ushort As[128 * LDA];
    __shared__ ushort Bs[COLS * LDA];

    const int t = threadIdx.x;
    const int w = t >> 6, lane = t & 63;
    const int l15 = lane & 15, quad = lane >> 4;
    const int wr = (w / WGC) * WTM, wc = (w % WGC) * 64;
    const int row0 = blockIdx.x * 128;

    f32x4 acc[MI][NI];
#pragma unroll
    for (int mi = 0; mi < MI; ++mi)
#pragma unroll
        for (int ni = 0; ni < NI; ++ni)
            acc[mi][ni] = (f32x4){0.f, 0.f, 0.f, 0.f};

    const int KT = FUSE2 ? 8 : 4;
    for (int kt = 0; kt < KT; ++kt) {
        const ushort* __restrict__ A = (FUSE2 && kt >= 4) ? A2 : A1;
        const ushort* __restrict__ W = (FUSE2 && kt >= 4) ? W2t : W1t;
        const int k0 = (kt & 3) * 32;
        __syncthreads();
        // stage A: 128 rows x 32 k = 512 slots of 8 halfwords
#pragma unroll
        for (int i = 0; i < 2; ++i) {
            int slot = t + i * 256;
            int r = slot >> 2, ko = (slot & 3) * 8;
            int row = row0 + r;
            if (row >= M) row = M - 1;
            bf16x8 v = *(const bf16x8*)&A[(size_t)row * K + k0 + ko];
            *(bf16x8*)&As[r * LDA + ko] = v;
        }
        // stage B: COLS rows x 32 k
#pragma unroll
        for (int i = 0; i < COLS / 64; ++i) {
            int slot = t + i * 256;
            int r = slot >> 2, ko = (slot & 3) * 8;
            bf16x8 v = *(const bf16x8*)&W[(size_t)r * K + k0 + ko];
            *(bf16x8*)&Bs[r * LDA + ko] = v;
        }
        __syncthreads();
        bf16x8 af[MI];
#pragma unroll
        for (int mi = 0; mi < MI; ++mi)
            af[mi] = *(const bf16x8*)&As[(wr + mi * 16 + l15) * LDA + quad * 8];
#pragma unroll
        for (int ni = 0; ni < NI; ++ni) {
            bf16x8 bfr = *(const bf16x8*)&Bs[(wc + ni * 16 + l15) * LDA + quad * 8];
#pragma unroll
            for (int mi = 0; mi < MI; ++mi)
                acc[mi][ni] = __builtin_amdgcn_mfma_f32_16x16x32_bf16(
                    af[mi], bfr, acc[mi][ni], 0, 0, 0);
        }
    }
    // epilogue
#pragma unroll
    for (int ni = 0; ni < NI; ++ni) {
        int c = wc + ni * 16 + l15;
        float bv = bias[c];
#pragma unroll
        for (int mi = 0; mi < MI; ++mi) {
#pragma unroll
            for (int r = 0; r < 4; ++r) {
                int row = row0 + wr + mi * 16 + quad * 4 + r;
                if (row < M) {
                    float v = acc[mi][ni][r] + bv;
                    if (RELU) v = fmaxf(v, 0.f);
                    if (OUTB)
                        ((ushort*)Cout)[(size_t)row * COLS + c] = f2b(v);
                    else
                        ((float*)Cout)[(size_t)row * COLS + c] = v;
                }
            }
        }
    }
}

extern "C" void kernel_launch(void* const* d_in, const int* in_sizes, int n_in,
                              void* d_out, int out_size, void* d_ws, size_t ws_size,
                              hipStream_t stream) {
    const float* x        = (const float*)d_in[0];
    const float* W_self1  = (const float*)d_in[1];
    const float* W_neigh1 = (const float*)d_in[2];
    const float* b1       = (const float*)d_in[3];
    const float* W_self2  = (const float*)d_in[4];
    const float* W_neigh2 = (const float*)d_in[5];
    const float* b2       = (const float*)d_in[6];
    const float* W_out    = (const float*)d_in[7];
    const float* b_out    = (const float*)d_in[8];
    const int* edge_src   = (const int*)d_in[9];
    const int* edge_dst   = (const int*)d_in[10];

    const int N = in_sizes[0] / N_FEATS;   // 100000
    const int E = in_sizes[9];             // 1600000
    float* out = (float*)d_out;

    char* ws = (char*)d_ws;
    size_t o = 0;
    auto carve = [&](size_t bytes) -> char* {
        char* p = ws + o;
        o += (bytes + 255) & ~(size_t)255;
        return p;
    };
    ushort* xb       = (ushort*)carve((size_t)N * N_FEATS * 2);
    ushort* h        = (ushort*)carve((size_t)N * N_FEATS * 2);
    ushort* hn       = (ushort*)carve((size_t)N * N_FEATS * 2);
    ushort* Ws1t     = (ushort*)carve(128 * 128 * 2);
    ushort* Wn1t     = (ushort*)carve(128 * 128 * 2);
    ushort* Ws2t     = (ushort*)carve(128 * 128 * 2);
    ushort* Wn2t     = (ushort*)carve(128 * 128 * 2);
    ushort* Wot      = (ushort*)carve(64 * 128 * 2);
    int* cnt         = (int*)carve((size_t)N * 4);
    int* row_start   = (int*)carve((size_t)(N + 1) * 4);
    int* rank        = (int*)carve((size_t)E * 4);
    int* blk         = (int*)carve(512 * 4);
    int* col         = (int*)carve((size_t)E * 4);
    (void)ws_size;

    const int NB = (N + 255) / 256;

    // CSR build
    hipMemsetAsync(cnt, 0, (size_t)N * 4, stream);
    k_count<<<(E + 255) / 256, 256, 0, stream>>>(edge_dst, cnt, rank, E);
    k_scan_local<<<NB, 256, 0, stream>>>(cnt, row_start, blk, N);
    k_scan_blk<<<1, 512, 0, stream>>>(blk, NB);
    k_scan_add<<<NB, 256, 0, stream>>>(row_start, blk, N, E);
    k_fill<<<(E + 255) / 256, 256, 0, stream>>>(edge_src, edge_dst, row_start, rank, col, E);

    // dtype prep
    k_f2b4<<<((N * N_FEATS / 4) + 255) / 256, 256, 0, stream>>>(x, xb, N * N_FEATS / 4);
    k_wt<<<(128 * 128 + 255) / 256, 256, 0, stream>>>(W_self1, Ws1t, 128, 128);
    k_wt<<<(128 * 128 + 255) / 256, 256, 0, stream>>>(W_neigh1, Wn1t, 128, 128);
    k_wt<<<(128 * 128 + 255) / 256, 256, 0, stream>>>(W_self2, Ws2t, 128, 128);
    k_wt<<<(128 * 128 + 255) / 256, 256, 0, stream>>>(W_neigh2, Wn2t, 128, 128);
    k_wt<<<(128 * 64 + 255) / 256, 256, 0, stream>>>(W_out, Wot, 128, 64);

    const int GB = (N + 127) / 128;
    const int AB = (N + 3) / 4;

    // layer 1
    k_agg<<<AB, 256, 0, stream>>>(xb, row_start, col, hn, N);
    k_mm<128, true, true, true><<<GB, 256, 0, stream>>>(xb, Ws1t, hn, Wn1t, b1, h, N);
    // layer 2 (in-place h: each block reads only its own 128-row slab)
    k_agg<<<AB, 256, 0, stream>>>(h, row_start, col, hn, N);
    k_mm<128, true, true, true><<<GB, 256, 0, stream>>>(h, Ws2t, hn, Wn2t, b2, h, N);
    // classifier
    k_mm<64, false, false, false><<<GB, 256, 0, stream>>>(h, Wot, nullptr, nullptr, b_out, out, N);
}

// Round 3
// 420.677 us; speedup vs baseline: 1.7756x; 1.4370x over previous
//
#include <hip/hip_runtime.h>
#include <hip/hip_bf16.h>

// GraphSAGE: 2x SAGEConv(mean) + ReLU + linear classifier.
// Round 3: MLP-restructured aggregation (4 edges x 16B/lane in flight),
// bf16 MFMA GEMMs, rank-trick CSR fill.

#define N_FEATS 128

typedef __attribute__((ext_vector_type(8))) short bf16x8;
typedef __attribute__((ext_vector_type(4))) float f32x4;

__device__ __forceinline__ ushort f2b(float f) {
    union { float f; unsigned u; } c; c.f = f;
    unsigned u = c.u + 0x7fffu + ((c.u >> 16) & 1u);
    return (ushort)(u >> 16);
}
__device__ __forceinline__ float b2f(ushort b) {
    union { unsigned u; float f; } c; c.u = ((unsigned)b) << 16;
    return c.f;
}

// ---------------- CSR build ----------------

__global__ void k_count(const int* __restrict__ dst, int* __restrict__ cnt,
                        int* __restrict__ rank, int E) {
    int i = blockIdx.x * blockDim.x + threadIdx.x;
    if (i < E) rank[i] = atomicAdd(&cnt[dst[i]], 1);
}

__global__ void k_scan_local(const int* __restrict__ cnt, int* __restrict__ excl,
                             int* __restrict__ blksum, int N) {
    __shared__ int s[256];
    int t = threadIdx.x;
    int i = blockIdx.x * 256 + t;
    int v = (i < N) ? cnt[i] : 0;
    s[t] = v;
    __syncthreads();
    for (int off = 1; off < 256; off <<= 1) {
        int x = 0;
        if (t >= off) x = s[t - off];
        __syncthreads();
        if (t >= off) s[t] += x;
        __syncthreads();
    }
    if (i < N) excl[i] = s[t] - v;
    if (t == 255) blksum[blockIdx.x] = s[255];
}

__global__ void k_scan_blk(int* __restrict__ blk, int NB) {
    __shared__ int s[512];
    int t = threadIdx.x;
    int v = (t < NB) ? blk[t] : 0;
    s[t] = v;
    __syncthreads();
    for (int off = 1; off < 512; off <<= 1) {
        int x = 0;
        if (t >= off) x = s[t - off];
        __syncthreads();
        if (t >= off) s[t] += x;
        __syncthreads();
    }
    if (t < NB) blk[t] = s[t] - v;
}

__global__ void k_scan_add(int* __restrict__ excl, const int* __restrict__ blk,
                           int N, int E) {
    int i = blockIdx.x * 256 + threadIdx.x;
    if (i < N) excl[i] += blk[blockIdx.x];
    if (blockIdx.x == 0 && threadIdx.x == 0) excl[N] = E;
}

__global__ void k_fill(const int* __restrict__ src, const int* __restrict__ dst,
                       const int* __restrict__ row_start, const int* __restrict__ rank,
                       int* __restrict__ col, int E) {
    int i = blockIdx.x * blockDim.x + threadIdx.x;
    if (i < E) {
        int p = row_start[dst[i]] + rank[i];
        col[p] = src[i];
    }
}

// ---------------- dtype conversion ----------------

__global__ void k_f2b4(const float* __restrict__ in, ushort* __restrict__ out, int n4) {
    int i = blockIdx.x * blockDim.x + threadIdx.x;
    if (i < n4) {
        float4 v = ((const float4*)in)[i];
        ushort4 o;
        o.x = f2b(v.x); o.y = f2b(v.y); o.z = f2b(v.z); o.w = f2b(v.w);
        ((ushort4*)out)[i] = o;
    }
}

// W [K][N] fp32 -> Wt [N][K] bf16
__global__ void k_wt(const float* __restrict__ W, ushort* __restrict__ Wt, int K, int N) {
    int i = blockIdx.x * blockDim.x + threadIdx.x;
    if (i < K * N) {
        int k = i / N, n = i % N;
        Wt[n * K + k] = f2b(W[i]);
    }
}

// ---------------- mean aggregation (CSR gather, bf16, MLP-optimized) ----------------
// 256 threads = 4 waves; one wave per node. Lane (g = lane>>4, f = lane&15):
// subgroup g handles edge slot g; lane covers feats [f*8, f*8+8) = 16B.
// 16 edges per loop step -> 4 independent 16B loads in flight per lane.
__global__ __launch_bounds__(256) void k_agg(const ushort* __restrict__ h,
                                             const int* __restrict__ row_start,
                                             const int* __restrict__ col,
                                             ushort* __restrict__ hn, int N) {
    int n = blockIdx.x * 4 + (threadIdx.x >> 6);
    if (n >= N) return;
    int lane = threadIdx.x & 63;
    int g = lane >> 4;
    int f = lane & 15;
    int beg = row_start[n], end = row_start[n + 1];
    float acc[8];
#pragma unroll
    for (int k = 0; k < 8; ++k) acc[k] = 0.f;

    for (int j0 = beg; j0 < end; j0 += 16) {
        int ja = j0 + g;
        int jb = j0 + 4 + g;
        int jc = j0 + 8 + g;
        int jd = j0 + 12 + g;
        int last = end - 1;
        int sa = __builtin_nontemporal_load(&col[min(ja, last)]);
        int sb = __builtin_nontemporal_load(&col[min(jb, last)]);
        int sc = __builtin_nontemporal_load(&col[min(jc, last)]);
        int sd = __builtin_nontemporal_load(&col[min(jd, last)]);
        bf16x8 va = *(const bf16x8*)&h[(size_t)sa * N_FEATS + f * 8];
        bf16x8 vb = *(const bf16x8*)&h[(size_t)sb * N_FEATS + f * 8];
        bf16x8 vc = *(const bf16x8*)&h[(size_t)sc * N_FEATS + f * 8];
        bf16x8 vd = *(const bf16x8*)&h[(size_t)sd * N_FEATS + f * 8];
        bool pa = ja < end, pb = jb < end, pc = jc < end, pd = jd < end;
#pragma unroll
        for (int k = 0; k < 8; ++k) {
            acc[k] += pa ? b2f((ushort)va[k]) : 0.f;
            acc[k] += pb ? b2f((ushort)vb[k]) : 0.f;
            acc[k] += pc ? b2f((ushort)vc[k]) : 0.f;
            acc[k] += pd ? b2f((ushort)vd[k]) : 0.f;
        }
    }
    // reduce across the 4 edge subgroups (lanes f, f+16, f+32, f+48)
#pragma unroll
    for (int k = 0; k < 8; ++k) {
        acc[k] += __shfl_xor(acc[k], 16, 64);
        acc[k] += __shfl_xor(acc[k], 32, 64);
    }
    if (g == 0) {
        float inv = 1.f / fmaxf((float)(end - beg), 1.f);
        bf16x8 o;
#pragma unroll
        for (int k = 0; k < 8; ++k) o[k] = (short)f2b(acc[k] * inv);
        *(bf16x8*)&hn[(size_t)n * N_FEATS + f * 8] = o;
    }
}

// ---------------- MFMA GEMM: C = act(A1@W1t' [+ A2@W2t'] + b) ----------------
// A: [M][128] bf16 row-major. Wt: [COLS][128] bf16 (pre-transposed).
// Block tile 128 x COLS, K=128 per phase. 256 threads = 4 waves.
template <int COLS, bool FUSE2, bool RELU, bool OUTB>
__global__ __launch_bounds__(256) void k_mm(const ushort* __restrict__ A1,
                                            const ushort* __restrict__ W1t,
                                            const ushort* __restrict__ A2,
                                            const ushort* __restrict__ W2t,
                                            const float* __restrict__ bias,
                                            void* __restrict__ Cout, int M) {
    constexpr int K = 128;
    constexpr int WGC = (COLS == 128) ? 2 : 1;   // wave grid cols
    constexpr int WTM = (COLS == 128) ? 64 : 32; // wave tile rows
    constexpr int MI = WTM / 16;
    constexpr int NI = 4;                        // 64 cols / 16
    constexpr int LDA = 40;                      // padded stride (halfwords)
    __shared__ ushort As[128 * LDA];
    __shared__ ushort Bs[COLS * LDA];

    const int t = threadIdx.x;
    const int w = t >> 6, lane = t & 63;
    const int l15 = lane & 15, quad = lane >> 4;
    const int wr = (w / WGC) * WTM, wc = (w % WGC) * 64;
    const int row0 = blockIdx.x * 128;

    f32x4 acc[MI][NI];
#pragma unroll
    for (int mi = 0; mi < MI; ++mi)
#pragma unroll
        for (int ni = 0; ni < NI; ++ni)
            acc[mi][ni] = (f32x4){0.f, 0.f, 0.f, 0.f};

    const int KT = FUSE2 ? 8 : 4;
    for (int kt = 0; kt < KT; ++kt) {
        const ushort* __restrict__ A = (FUSE2 && kt >= 4) ? A2 : A1;
        const ushort* __restrict__ W = (FUSE2 && kt >= 4) ? W2t : W1t;
        const int k0 = (kt & 3) * 32;
        __syncthreads();
        // stage A: 128 rows x 32 k = 512 slots of 8 halfwords
#pragma unroll
        for (int i = 0; i < 2; ++i) {
            int slot = t + i * 256;
            int r = slot >> 2, ko = (slot & 3) * 8;
            int row = row0 + r;
            if (row >= M) row = M - 1;
            bf16x8 v = *(const bf16x8*)&A[(size_t)row * K + k0 + ko];
            *(bf16x8*)&As[r * LDA + ko] = v;
        }
        // stage B: COLS rows x 32 k
#pragma unroll
        for (int i = 0; i < COLS / 64; ++i) {
            int slot = t + i * 256;
            int r = slot >> 2, ko = (slot & 3) * 8;
            bf16x8 v = *(const bf16x8*)&W[(size_t)r * K + k0 + ko];
            *(bf16x8*)&Bs[r * LDA + ko] = v;
        }
        __syncthreads();
        bf16x8 af[MI];
#pragma unroll
        for (int mi = 0; mi < MI; ++mi)
            af[mi] = *(const bf16x8*)&As[(wr + mi * 16 + l15) * LDA + quad * 8];
#pragma unroll
        for (int ni = 0; ni < NI; ++ni) {
            bf16x8 bfr = *(const bf16x8*)&Bs[(wc + ni * 16 + l15) * LDA + quad * 8];
#pragma unroll
            for (int mi = 0; mi < MI; ++mi)
                acc[mi][ni] = __builtin_amdgcn_mfma_f32_16x16x32_bf16(
                    af[mi], bfr, acc[mi][ni], 0, 0, 0);
        }
    }
    // epilogue
#pragma unroll
    for (int ni = 0; ni < NI; ++ni) {
        int c = wc + ni * 16 + l15;
        float bv = bias[c];
#pragma unroll
        for (int mi = 0; mi < MI; ++mi) {
#pragma unroll
            for (int r = 0; r < 4; ++r) {
                int row = row0 + wr + mi * 16 + quad * 4 + r;
                if (row < M) {
                    float v = acc[mi][ni][r] + bv;
                    if (RELU) v = fmaxf(v, 0.f);
                    if (OUTB)
                        ((ushort*)Cout)[(size_t)row * COLS + c] = f2b(v);
                    else
                        ((float*)Cout)[(size_t)row * COLS + c] = v;
                }
            }
        }
    }
}

extern "C" void kernel_launch(void* const* d_in, const int* in_sizes, int n_in,
                              void* d_out, int out_size, void* d_ws, size_t ws_size,
                              hipStream_t stream) {
    const float* x        = (const float*)d_in[0];
    const float* W_self1  = (const float*)d_in[1];
    const float* W_neigh1 = (const float*)d_in[2];
    const float* b1       = (const float*)d_in[3];
    const float* W_self2  = (const float*)d_in[4];
    const float* W_neigh2 = (const float*)d_in[5];
    const float* b2       = (const float*)d_in[6];
    const float* W_out    = (const float*)d_in[7];
    const float* b_out    = (const float*)d_in[8];
    const int* edge_src   = (const int*)d_in[9];
    const int* edge_dst   = (const int*)d_in[10];

    const int N = in_sizes[0] / N_FEATS;   // 100000
    const int E = in_sizes[9];             // 1600000
    float* out = (float*)d_out;

    char* ws = (char*)d_ws;
    size_t o = 0;
    auto carve = [&](size_t bytes) -> char* {
        char* p = ws + o;
        o += (bytes + 255) & ~(size_t)255;
        return p;
    };
    ushort* xb       = (ushort*)carve((size_t)N * N_FEATS * 2);
    ushort* h        = (ushort*)carve((size_t)N * N_FEATS * 2);
    ushort* hn       = (ushort*)carve((size_t)N * N_FEATS * 2);
    ushort* Ws1t     = (ushort*)carve(128 * 128 * 2);
    ushort* Wn1t     = (ushort*)carve(128 * 128 * 2);
    ushort* Ws2t     = (ushort*)carve(128 * 128 * 2);
    ushort* Wn2t     = (ushort*)carve(128 * 128 * 2);
    ushort* Wot      = (ushort*)carve(64 * 128 * 2);
    int* cnt         = (int*)carve((size_t)N * 4);
    int* row_start   = (int*)carve((size_t)(N + 1) * 4);
    int* rank        = (int*)carve((size_t)E * 4);
    int* blk         = (int*)carve(512 * 4);
    int* col         = (int*)carve((size_t)E * 4);
    (void)ws_size;

    const int NB = (N + 255) / 256;

    // CSR build
    hipMemsetAsync(cnt, 0, (size_t)N * 4, stream);
    k_count<<<(E + 255) / 256, 256, 0, stream>>>(edge_dst, cnt, rank, E);
    k_scan_local<<<NB, 256, 0, stream>>>(cnt, row_start, blk, N);
    k_scan_blk<<<1, 512, 0, stream>>>(blk, NB);
    k_scan_add<<<NB, 256, 0, stream>>>(row_start, blk, N, E);
    k_fill<<<(E + 255) / 256, 256, 0, stream>>>(edge_src, edge_dst, row_start, rank, col, E);

    // dtype prep
    k_f2b4<<<((N * N_FEATS / 4) + 255) / 256, 256, 0, stream>>>(x, xb, N * N_FEATS / 4);
    k_wt<<<(128 * 128 + 255) / 256, 256, 0, stream>>>(W_self1, Ws1t, 128, 128);
    k_wt<<<(128 * 128 + 255) / 256, 256, 0, stream>>>(W_neigh1, Wn1t, 128, 128);
    k_wt<<<(128 * 128 + 255) / 256, 256, 0, stream>>>(W_self2, Ws2t, 128, 128);
    k_wt<<<(128 * 128 + 255) / 256, 256, 0, stream>>>(W_neigh2, Wn2t, 128, 128);
    k_wt<<<(128 * 64 + 255) / 256, 256, 0, stream>>>(W_out, Wot, 128, 64);

    const int GB = (N + 127) / 128;
    const int AB = (N + 3) / 4;

    // layer 1
    k_agg<<<AB, 256, 0, stream>>>(xb, row_start, col, hn, N);
    k_mm<128, true, true, true><<<GB, 256, 0, stream>>>(xb, Ws1t, hn, Wn1t, b1, h, N);
    // layer 2 (in-place h: each block reads only its own 128-row slab)
    k_agg<<<AB, 256, 0, stream>>>(h, row_start, col, hn, N);
    k_mm<128, true, true, true><<<GB, 256, 0, stream>>>(h, Ws2t, hn, Wn2t, b2, h, N);
    // classifier
    k_mm<64, false, false, false><<<GB, 256, 0, stream>>>(h, Wot, nullptr, nullptr, b_out, out, N);
}